// Round 1
// baseline (159.999 us; speedup 1.0000x reference)
//
#include <hip/hip_runtime.h>

// Problem constants (fixed by the reference).
constexpr int N_SAE  = 128;
constexpr int D_DATA = 128;
constexpr int D_DICT = 512;
constexpr int B_TOK  = 1024;

constexpr int TILE_T = 16;   // tokens per tile (avg tokens per block ~8, max ~32)
constexpr int NT     = 256;  // threads per block
constexpr int SPLIT  = 2;    // blocks per expert (token-parity partition)

__global__ __launch_bounds__(NT)
void moe_sae_kernel(const float* __restrict__ x,
                    const float* __restrict__ gate,
                    const float* __restrict__ W_enc,
                    const float* __restrict__ W_dec,
                    const float* __restrict__ b_enc,
                    const float* __restrict__ b_dec,
                    float* __restrict__ out)
{
    const int e   = blockIdx.x;   // expert id
    const int h   = blockIdx.y;   // token-parity half
    const int tid = threadIdx.x;

    __shared__ int   s_tok[B_TOK / SPLIT];   // token ids routed to this (expert, half)
    __shared__ float s_g[B_TOK / SPLIT];     // their gate values
    __shared__ int   s_count;
    __shared__ float s_x[TILE_T][D_DATA];    // 8 KB
    __shared__ float s_acts[TILE_T][D_DICT]; // 32 KB  (holds g * relu(enc))

    // ---- Phase 1: scan this expert's gate column, compact active tokens ----
    if (tid == 0) s_count = 0;
    __syncthreads();
    for (int t = tid; t < B_TOK; t += NT) {
        if ((t & (SPLIT - 1)) != h) continue;
        float gv = gate[(size_t)t * N_SAE + e];
        if (gv != 0.0f) {
            int slot = atomicAdd(&s_count, 1);
            s_tok[slot] = t;
            s_g[slot]   = gv;
        }
    }
    __syncthreads();
    const int n = s_count;
    if (n == 0) return;

    const float2* We2 = (const float2*)(W_enc + (size_t)e * D_DATA * D_DICT);
    const float2* Wd2 = (const float2*)(W_dec + (size_t)e * D_DICT * D_DATA);
    const float2  be  = ((const float2*)(b_enc + (size_t)e * D_DICT))[tid];      // cols 2*tid, 2*tid+1
    const int dp = tid & 63;        // decode: d-pair index (covers 128 cols as float2)
    const int hh = tid >> 6;        // decode: token subgroup 0..3
    const float2  bd  = ((const float2*)(b_dec + (size_t)e * D_DATA))[dp];

    for (int t0 = 0; t0 < n; t0 += TILE_T) {
        const int tcnt = min(TILE_T, n - t0);

        // ---- load x tile (coalesced float4) ----
        for (int i = tid; i < tcnt * (D_DATA / 4); i += NT) {
            int tt = i >> 5;          // / 32
            int dd = i & 31;          // % 32
            ((float4*)s_x[tt])[dd] =
                ((const float4*)(x + (size_t)s_tok[t0 + tt] * D_DATA))[dd];
        }
        __syncthreads();

        // ---- encode: thread tid owns dict columns (2*tid, 2*tid+1) ----
        {
            float acc0[TILE_T], acc1[TILE_T];
            #pragma unroll
            for (int t = 0; t < TILE_T; ++t) { acc0[t] = be.x; acc1[t] = be.y; }
            for (int d = 0; d < D_DATA; d += 4) {
                float2 w0 = We2[(d + 0) * (D_DICT / 2) + tid];
                float2 w1 = We2[(d + 1) * (D_DICT / 2) + tid];
                float2 w2 = We2[(d + 2) * (D_DICT / 2) + tid];
                float2 w3 = We2[(d + 3) * (D_DICT / 2) + tid];
                #pragma unroll
                for (int t = 0; t < TILE_T; ++t) {
                    float4 xv = *(const float4*)&s_x[t][d];   // wave-uniform broadcast
                    acc0[t] = fmaf(xv.x, w0.x, acc0[t]); acc1[t] = fmaf(xv.x, w0.y, acc1[t]);
                    acc0[t] = fmaf(xv.y, w1.x, acc0[t]); acc1[t] = fmaf(xv.y, w1.y, acc1[t]);
                    acc0[t] = fmaf(xv.z, w2.x, acc0[t]); acc1[t] = fmaf(xv.z, w2.y, acc1[t]);
                    acc0[t] = fmaf(xv.w, w3.x, acc0[t]); acc1[t] = fmaf(xv.w, w3.y, acc1[t]);
                }
            }
            #pragma unroll
            for (int t = 0; t < TILE_T; ++t) {
                if (t < tcnt) {
                    float g = s_g[t0 + t];
                    float2 a;
                    a.x = fmaxf(acc0[t], 0.0f) * g;
                    a.y = fmaxf(acc1[t], 0.0f) * g;
                    ((float2*)s_acts[t])[tid] = a;
                }
            }
        }
        __syncthreads();

        // ---- decode: thread (dp, hh) owns out cols (2*dp,2*dp+1), tokens 4*i+hh ----
        {
            float accA[TILE_T / 4], accB[TILE_T / 4];
            #pragma unroll
            for (int i = 0; i < TILE_T / 4; ++i) { accA[i] = 0.0f; accB[i] = 0.0f; }
            for (int ee = 0; ee < D_DICT; ee += 4) {
                float2 w0 = Wd2[(ee + 0) * (D_DATA / 2) + dp];
                float2 w1 = Wd2[(ee + 1) * (D_DATA / 2) + dp];
                float2 w2 = Wd2[(ee + 2) * (D_DATA / 2) + dp];
                float2 w3 = Wd2[(ee + 3) * (D_DATA / 2) + dp];
                #pragma unroll
                for (int i = 0; i < TILE_T / 4; ++i) {
                    float4 av = *(const float4*)&s_acts[4 * i + hh][ee];  // broadcast
                    accA[i] = fmaf(av.x, w0.x, accA[i]); accB[i] = fmaf(av.x, w0.y, accB[i]);
                    accA[i] = fmaf(av.y, w1.x, accA[i]); accB[i] = fmaf(av.y, w1.y, accB[i]);
                    accA[i] = fmaf(av.z, w2.x, accA[i]); accB[i] = fmaf(av.z, w2.y, accB[i]);
                    accA[i] = fmaf(av.w, w3.x, accA[i]); accB[i] = fmaf(av.w, w3.y, accB[i]);
                }
            }
            #pragma unroll
            for (int i = 0; i < TILE_T / 4; ++i) {
                int t = 4 * i + hh;
                if (t < tcnt) {
                    float* op = out + (size_t)s_tok[t0 + t] * D_DATA + 2 * dp;
                    atomicAdd(op,     accA[i] + bd.x);
                    atomicAdd(op + 1, accB[i] + bd.y);
                }
            }
        }
        __syncthreads();
    }
}

extern "C" void kernel_launch(void* const* d_in, const int* in_sizes, int n_in,
                              void* d_out, int out_size, void* d_ws, size_t ws_size,
                              hipStream_t stream) {
    const float* x     = (const float*)d_in[0];
    const float* gate  = (const float*)d_in[1];
    const float* W_enc = (const float*)d_in[2];
    const float* W_dec = (const float*)d_in[3];
    const float* b_enc = (const float*)d_in[4];
    const float* b_dec = (const float*)d_in[5];
    float* out = (float*)d_out;

    // d_out is poisoned (0xAA) before every timed launch; we accumulate into it.
    hipMemsetAsync(d_out, 0, (size_t)out_size * sizeof(float), stream);

    dim3 grid(N_SAE, SPLIT);
    moe_sae_kernel<<<grid, NT, 0, stream>>>(x, gate, W_enc, W_dec, b_enc, b_dec, out);
}

// Round 2
// 141.226 us; speedup vs baseline: 1.1329x; 1.1329x over previous
//
#include <hip/hip_runtime.h>

// Problem constants (fixed by the reference).
constexpr int N_SAE  = 128;
constexpr int D_DATA = 128;
constexpr int D_DICT = 512;
constexpr int B_TOK  = 1024;

constexpr int TILE_T = 16;           // tokens per tile
constexpr int NT     = 256;          // threads per block
constexpr int SPLIT  = 2;            // blocks per expert along tokens (parity)
constexpr int NCHUNK = 4;            // blocks per expert along dict dim
constexpr int CW     = D_DICT / NCHUNK;  // 128 dict cols per chunk

__global__ __launch_bounds__(NT)
void moe_sae_kernel(const float* __restrict__ x,
                    const float* __restrict__ gate,
                    const float* __restrict__ W_enc,
                    const float* __restrict__ W_dec,
                    const float* __restrict__ b_enc,
                    const float* __restrict__ b_dec,
                    float* __restrict__ out)
{
    const int e   = blockIdx.x;   // expert id
    const int c   = blockIdx.y;   // dict chunk id
    const int h   = blockIdx.z;   // token-parity half
    const int tid = threadIdx.x;
    const int c0  = c * CW;

    __shared__ int   s_tok[B_TOK / SPLIT];
    __shared__ float s_g[B_TOK / SPLIT];
    __shared__ int   s_count;
    __shared__ float s_x[TILE_T][D_DATA];   // 8 KB
    __shared__ float s_acts[TILE_T][CW];    // 8 KB (g * relu(enc), this chunk)

    // ---- Phase 1: scan this expert's gate column (our token half), compact ----
    if (tid == 0) s_count = 0;
    __syncthreads();
    for (int i = tid; i < B_TOK / SPLIT; i += NT) {
        int t = i * SPLIT + h;
        float gv = gate[(size_t)t * N_SAE + e];
        if (gv != 0.0f) {
            int slot = atomicAdd(&s_count, 1);
            s_tok[slot] = t;
            s_g[slot]   = gv;
        }
    }
    __syncthreads();
    const int n = s_count;
    if (n == 0) return;

    const float*  We  = W_enc + (size_t)e * D_DATA * D_DICT;   // [128][512]
    const float2* Wd2 = (const float2*)(W_dec + (size_t)e * D_DICT * D_DATA); // [512][64 x float2]

    // encode mapping: col = c0 + (tid&127), token-group tg = tid>>7 (8 tokens each)
    const int ecol = tid & (CW - 1);
    const int tg   = tid >> 7;
    const float be = b_enc[(size_t)e * D_DICT + c0 + ecol];

    // decode mapping: dp = tid&63 -> out cols (2*dp, 2*dp+1); hh = tid>>6 -> 4 tokens
    const int dp = tid & 63;
    const int hh = tid >> 6;
    const float2 bd = ((const float2*)(b_dec + (size_t)e * D_DATA))[dp];

    for (int t0 = 0; t0 < n; t0 += TILE_T) {
        const int tcnt = min(TILE_T, n - t0);

        // ---- load x tile (coalesced float4) ----
        for (int i = tid; i < tcnt * (D_DATA / 4); i += NT) {
            int tt = i >> 5;          // / 32
            int dd = i & 31;          // % 32
            ((float4*)s_x[tt])[dd] =
                ((const float4*)(x + (size_t)s_tok[t0 + tt] * D_DATA))[dd];
        }
        __syncthreads();

        // ---- encode: thread owns dict col (c0+ecol), tokens [tg*8, tg*8+8) ----
        {
            float acc[8];
            #pragma unroll
            for (int j = 0; j < 8; ++j) acc[j] = be;
            for (int d = 0; d < D_DATA; d += 4) {
                float w0 = We[(size_t)(d + 0) * D_DICT + c0 + ecol];
                float w1 = We[(size_t)(d + 1) * D_DICT + c0 + ecol];
                float w2 = We[(size_t)(d + 2) * D_DICT + c0 + ecol];
                float w3 = We[(size_t)(d + 3) * D_DICT + c0 + ecol];
                #pragma unroll
                for (int j = 0; j < 8; ++j) {
                    float4 xv = *(const float4*)&s_x[tg * 8 + j][d];  // broadcast
                    acc[j] = fmaf(xv.x, w0, acc[j]);
                    acc[j] = fmaf(xv.y, w1, acc[j]);
                    acc[j] = fmaf(xv.z, w2, acc[j]);
                    acc[j] = fmaf(xv.w, w3, acc[j]);
                }
            }
            #pragma unroll
            for (int j = 0; j < 8; ++j) {
                int t = tg * 8 + j;
                if (t < tcnt) {
                    s_acts[t][ecol] = fmaxf(acc[j], 0.0f) * s_g[t0 + t];
                }
            }
        }
        __syncthreads();

        // ---- decode (partial over this chunk's 128 dict rows) ----
        {
            float accA[4], accB[4];
            #pragma unroll
            for (int j = 0; j < 4; ++j) { accA[j] = 0.0f; accB[j] = 0.0f; }
            for (int ee = 0; ee < CW; ee += 4) {
                float2 w0 = Wd2[(size_t)(c0 + ee + 0) * (D_DATA / 2) + dp];
                float2 w1 = Wd2[(size_t)(c0 + ee + 1) * (D_DATA / 2) + dp];
                float2 w2 = Wd2[(size_t)(c0 + ee + 2) * (D_DATA / 2) + dp];
                float2 w3 = Wd2[(size_t)(c0 + ee + 3) * (D_DATA / 2) + dp];
                #pragma unroll
                for (int j = 0; j < 4; ++j) {
                    float4 av = *(const float4*)&s_acts[4 * j + hh][ee];  // broadcast
                    accA[j] = fmaf(av.x, w0.x, accA[j]); accB[j] = fmaf(av.x, w0.y, accB[j]);
                    accA[j] = fmaf(av.y, w1.x, accA[j]); accB[j] = fmaf(av.y, w1.y, accB[j]);
                    accA[j] = fmaf(av.z, w2.x, accA[j]); accB[j] = fmaf(av.z, w2.y, accB[j]);
                    accA[j] = fmaf(av.w, w3.x, accA[j]); accB[j] = fmaf(av.w, w3.y, accB[j]);
                }
            }
            #pragma unroll
            for (int j = 0; j < 4; ++j) {
                int t = 4 * j + hh;
                if (t < tcnt) {
                    float* op = out + (size_t)s_tok[t0 + t] * D_DATA + 2 * dp;
                    // b_dec added exactly once per (token, expert) pair: by chunk 0
                    float addA = accA[j] + (c == 0 ? bd.x : 0.0f);
                    float addB = accB[j] + (c == 0 ? bd.y : 0.0f);
                    atomicAdd(op,     addA);
                    atomicAdd(op + 1, addB);
                }
            }
        }
        __syncthreads();
    }
}

extern "C" void kernel_launch(void* const* d_in, const int* in_sizes, int n_in,
                              void* d_out, int out_size, void* d_ws, size_t ws_size,
                              hipStream_t stream) {
    const float* x     = (const float*)d_in[0];
    const float* gate  = (const float*)d_in[1];
    const float* W_enc = (const float*)d_in[2];
    const float* W_dec = (const float*)d_in[3];
    const float* b_enc = (const float*)d_in[4];
    const float* b_dec = (const float*)d_in[5];
    float* out = (float*)d_out;

    // d_out is poisoned (0xAA) before every timed launch; we accumulate into it.
    hipMemsetAsync(d_out, 0, (size_t)out_size * sizeof(float), stream);

    dim3 grid(N_SAE, NCHUNK, SPLIT);
    moe_sae_kernel<<<grid, NT, 0, stream>>>(x, gate, W_enc, W_dec, b_enc, b_dec, out);
}